// Round 4
// baseline (485.632 us; speedup 1.0000x reference)
//
#include <hip/hip_runtime.h>

#define H 256
#define W 256
#define CIN 16
#define COUT 16
#define OH 254
#define OW 254
#define HW (H * W)

#define OHB 4            // output rows computed per pipeline step
#define RING 10          // LDS ring rows (>= 2*OHB + 2)
#define COLS 259         // cols 0..255 data + 256..258 zero halo (quad overhang)
#define OHC 32           // oh rows per block
#define SPLIT 8          // chunks per image (8*32 = 256 >= 254)
#define STEPS (OHC / OHB)
#define NTHREADS 512

typedef int int4v __attribute__((ext_vector_type(4)));
typedef int int2v __attribute__((ext_vector_type(2)));
typedef float f2v  __attribute__((ext_vector_type(2)));

// pack low bytes of 4 dwords -> 1 dword: [d0.b0, d1.b0, d2.b0, d3.b0]
static __device__ __forceinline__ int pack4(int d0, int d1, int d2, int d3) {
    int t0 = __builtin_amdgcn_perm(d1, d0, 0x00000400);
    int t1 = __builtin_amdgcn_perm(d3, d2, 0x00000400);
    return __builtin_amdgcn_perm(t1, t0, 0x05040100);
}

// out[n][co][oh][ow] = 1e-4*(Sum x*w - 3*Sum(x) - 7*Sum(w) + 3024) + bdeq[co]
//
// Ring-pipelined implicit GEMM (A = pixels, B = weights; D row = ow ->
// vectorized stores). R4 change: the per-step prefetch is UNCONDITIONAL
// (row index clamped; dummy rows land in ring slots provably unused by the
// final steps) and the schedule is pinned with sched_barrier(0) fences so the
// 16 global loads issue BEFORE the MFMA phase and their vmcnt-wait lands at
// the pack phase after the latency is covered. R3's conditional prefetch got
// sunk to its use site by the scheduler (VGPR_Count=48 proves it: ld[16]
// alone needs 32) -- the pipeline existed in source but not in the asm.
__global__ __launch_bounds__(NTHREADS, 4) void conv_q8_ring(
    const int* __restrict__ x, const int* __restrict__ wq,
    const float* __restrict__ bias, float* __restrict__ out)
{
    __shared__ int4v lds_x[RING * COLS];  // [slot*COLS + col], 16 cin bytes/pixel
    __shared__ int4v lds_wB[192];         // [(kh*4 + kw)*16 + co]
    __shared__ int   lds_ci[COUT];        // -7*sumW + 3024
    __shared__ float lds_bf[COUT];        // dequantized bias

    const int tid   = threadIdx.x;
    const int chunk = blockIdx.x;
    const int n     = blockIdx.y;
    const int oh0   = chunk * OHC;
    const int* xn   = x + (size_t)n * (CIN * HW);

    // ---- stage packed B (weights) ----
    if (tid < 192) {
        const int co = tid & 15;
        const int kw = (tid >> 4) & 3;
        const int kh = tid >> 6;
        int4v pk = {0, 0, 0, 0};
        if (kw < 3) {
#pragma unroll
            for (int q = 0; q < 4; ++q) {
                const int* wp = wq + ((co * CIN + q * 4) * 3 + kh) * 3 + kw;
                pk[q] = pack4(wp[0], wp[9], wp[18], wp[27]);
            }
        }
        lds_wB[tid] = pk;
    }
    // ---- per-cout constants ----
    if (tid < COUT) {
        int s = 0;
        const int* wc = wq + tid * CIN * 9;
#pragma unroll
        for (int k = 0; k < CIN * 9; ++k) s += wc[k];
        lds_ci[tid] = -7 * s + 144 * 21;
        float r = rintf(bias[tid] * 10000.0f);                // round-half-even
        r = fminf(fmaxf(r, -2147483648.0f), 2147483647.0f);   // clamp int32 range
        lds_bf[tid] = r * 1e-4f;
    }
    // ---- zero halo columns 256..258 in every ring slot (never overwritten) ----
    if (tid < RING * 3) {
        const int slot = tid / 3;
        const int col  = 256 + (tid % 3);
        lds_x[slot * COLS + col] = (int4v){0, 0, 0, 0};
    }

    // ---- prologue: stage input rows oh0 .. oh0+5 ----
    for (int t = tid; t < 6 * 128; t += NTHREADS) {
        const int rloc = t >> 7;
        const int c2   = (t & 127) * 2;
        const int iru  = oh0 + rloc;
        const int ih   = (iru < H) ? iru : H - 1;
        const int* p = xn + ih * W + c2;
        int4v pk0, pk1;
#pragma unroll
        for (int q = 0; q < 4; ++q) {
            const int2v d0 = *(const int2v*)(p + (q * 4 + 0) * HW);
            const int2v d1 = *(const int2v*)(p + (q * 4 + 1) * HW);
            const int2v d2 = *(const int2v*)(p + (q * 4 + 2) * HW);
            const int2v d3 = *(const int2v*)(p + (q * 4 + 3) * HW);
            pk0[q] = pack4(d0.x, d1.x, d2.x, d3.x);
            pk1[q] = pack4(d0.y, d1.y, d2.y, d3.y);
        }
        const int slot = iru % RING;
        lds_x[slot * COLS + c2]     = pk0;
        lds_x[slot * COLS + c2 + 1] = pk1;
    }
    __syncthreads();

    const int wave = tid >> 6;
    const int lane = tid & 63;
    const int n16  = lane & 15;
    const int quad = lane >> 4;
    const int coff = n16 + quad;

    const int4v w0 = lds_wB[(0 * 4 + quad) * 16 + n16];
    const int4v w1 = lds_wB[(1 * 4 + quad) * 16 + n16];
    const int4v w2 = lds_wB[(2 * 4 + quad) * 16 + n16];
    const int ov = (quad < 3) ? 0x01010101 : 0;
    const int4v bones = {ov, ov, ov, ov};
    const int   ci_s = lds_ci[n16];
    const float bf_s = lds_bf[n16];
    const int4v zero4 = {0, 0, 0, 0};

    const int rl    = wave >> 1;        // oh row within step (0..3)
    const int gbase = (wave & 1) * 8;   // 8 ow-groups per wave
    float* outn = out + (size_t)n * (COUT * OH * OW);

    // per-thread prefetch coordinates (fixed)
    const int rloc = tid >> 7;          // 0..3
    const int c2p  = (tid & 127) * 2;

    for (int s = 0; s < STEPS; ++s) {
        // ---- (a) issue next step's global loads -- UNCONDITIONAL ----
        // Last-step dummy rows (iru >= oh0+34) are clamped to row H-1 and land
        // in ring slots (4s+6..4s+9)%10, disjoint from the rows any remaining
        // compute reads ((4s..4s+5)%10): harmless.
        const int iru    = oh0 + 4 * s + 6 + rloc;
        const int slot_p = iru % RING;
        const int ih     = (iru < H) ? iru : H - 1;
        const int* p = xn + ih * W + c2p;
        int2v ld[16];
#pragma unroll
        for (int q = 0; q < 16; ++q)
            ld[q] = *(const int2v*)(p + q * HW);
        __builtin_amdgcn_sched_barrier(0);   // loads must issue before compute

        // ---- (b) compute current 4 rows ----
        const int oh  = oh0 + 4 * s + rl;
        const int sl0 = (oh    ) % RING;
        const int sl1 = (oh + 1) % RING;
        const int sl2 = (oh + 2) % RING;
        const bool do_store = (oh < OH);   // wave-uniform

#pragma unroll
        for (int gi = 0; gi < 8; ++gi) {
            const int g = gbase + gi;
            const int c = g * 16 + coff;
            const int4v p0 = lds_x[sl0 * COLS + c];
            const int4v p1 = lds_x[sl1 * COLS + c];
            const int4v p2 = lds_x[sl2 * COLS + c];
            int4v acc = __builtin_amdgcn_mfma_i32_16x16x64_i8(p0, w0, zero4, 0, 0, 0);
            acc = __builtin_amdgcn_mfma_i32_16x16x64_i8(p1, w1, acc, 0, 0, 0);
            acc = __builtin_amdgcn_mfma_i32_16x16x64_i8(p2, w2, acc, 0, 0, 0);
            int4v acs = __builtin_amdgcn_mfma_i32_16x16x64_i8(p0, bones, zero4, 0, 0, 0);
            acs = __builtin_amdgcn_mfma_i32_16x16x64_i8(p1, bones, acs, 0, 0, 0);
            acs = __builtin_amdgcn_mfma_i32_16x16x64_i8(p2, bones, acs, 0, 0, 0);
            if (do_store) {
                const int owb = g * 16 + quad * 4;
                float f0 = fmaf(1e-4f, (float)(acc[0] - 3 * acs[0] + ci_s), bf_s);
                float f1 = fmaf(1e-4f, (float)(acc[1] - 3 * acs[1] + ci_s), bf_s);
                float f2 = fmaf(1e-4f, (float)(acc[2] - 3 * acs[2] + ci_s), bf_s);
                float f3 = fmaf(1e-4f, (float)(acc[3] - 3 * acs[3] + ci_s), bf_s);
                float* ptr = outn + (n16 * OH + oh) * OW + owb;
                if (owb + 3 < OW) {           // always 8B-aligned: OW even, owb%4==0
                    *(f2v*)(ptr)     = (f2v){f0, f1};
                    *(f2v*)(ptr + 2) = (f2v){f2, f3};
                } else {                       // g==15, quad==3: ow 252..255 partial
                    if (owb + 0 < OW) ptr[0] = f0;
                    if (owb + 1 < OW) ptr[1] = f1;
                }
            }
        }
        __builtin_amdgcn_sched_barrier(0);   // keep pack/ds_write after compute

        // ---- (c) pack + commit staged rows to ring, (d) barrier ----
        {
            int4v pk0, pk1;
#pragma unroll
            for (int q = 0; q < 4; ++q) {
                pk0[q] = pack4(ld[4 * q].x, ld[4 * q + 1].x, ld[4 * q + 2].x, ld[4 * q + 3].x);
                pk1[q] = pack4(ld[4 * q].y, ld[4 * q + 1].y, ld[4 * q + 2].y, ld[4 * q + 3].y);
            }
            lds_x[slot_p * COLS + c2p]     = pk0;
            lds_x[slot_p * COLS + c2p + 1] = pk1;
            __syncthreads();
        }
    }
}

extern "C" void kernel_launch(void* const* d_in, const int* in_sizes, int n_in,
                              void* d_out, int out_size, void* d_ws, size_t ws_size,
                              hipStream_t stream) {
    const int*   x    = (const int*)d_in[0];
    const int*   wq   = (const int*)d_in[1];
    const float* bias = (const float*)d_in[2];
    float*       out  = (float*)d_out;

    const int n = in_sizes[0] / (CIN * H * W);   // 64
    dim3 grid(SPLIT, n);
    conv_q8_ring<<<grid, NTHREADS, 0, stream>>>(x, wq, bias, out);
}